// Round 3
// baseline (50.796 us; speedup 1.0000x reference)
//
#include <hip/hip_runtime.h>

// out[row][c] = x[row][c] + pe[row - seg_start(row)][c]
// O(1) segment lookup: bucket table (64 rows/bucket) + exclusive cumsum.
// D_MODEL = 1024 floats = 256 float4 per row.
__global__ void __launch_bounds__(512)
pe_fused_kernel(const float4* __restrict__ x,
                const float4* __restrict__ pe,
                const int* __restrict__ dia_len, int n_seg,
                float4* __restrict__ out, long n4) {
    __shared__ int ex[513];      // exclusive cumsum; seg s = rows [ex[s], ex[s+1])
    __shared__ int seg_lo[512];  // segment containing row b*64 (also scan scratch)
    const int t = threadIdx.x;

    // 1) load lengths into scan scratch
    seg_lo[t] = (t < n_seg) ? dia_len[t] : 0;
    __syncthreads();
    // 2) Hillis-Steele inclusive scan over 512 entries
    #pragma unroll
    for (int off = 1; off < 512; off <<= 1) {
        int add = (t >= off) ? seg_lo[t - off] : 0;
        __syncthreads();
        seg_lo[t] += add;
        __syncthreads();
    }
    // 3) exclusive cumsum with sentinel
    ex[t + 1] = seg_lo[t];
    if (t == 0) ex[0] = 0;
    __syncthreads();
    // 4) bucket table: segment t owns every bucket whose first row it contains
    if (t < n_seg) {
        const int st = ex[t], en = ex[t + 1];
        for (int b = (st + 63) >> 6; (b << 6) < en; ++b) seg_lo[b] = t;
    }
    __syncthreads();

    const long stride = (long)gridDim.x * blockDim.x;
    long i = (long)blockIdx.x * blockDim.x + threadIdx.x;

    #define PE_BODY(I)                                                \
        {                                                             \
            const int row = (int)((I) >> 8);                          \
            int s = seg_lo[row >> 6];                                 \
            while (ex[s + 1] <= row) ++s;  /* 0 iters when len>=64 */ \
            const int p = row - ex[s];                                \
            const float4 xv = x[(I)];                                 \
            const float4 pv = pe[((long)p << 8) | ((I) & 255)];       \
            float4 o;                                                 \
            o.x = xv.x + pv.x; o.y = xv.y + pv.y;                     \
            o.z = xv.z + pv.z; o.w = xv.w + pv.w;                     \
            out[(I)] = o;                                             \
        }

    // unroll x2: two independent load chains in flight
    for (; i + stride < n4; i += 2 * stride) {
        PE_BODY(i);
        PE_BODY(i + stride);
    }
    for (; i < n4; i += stride) PE_BODY(i);
    #undef PE_BODY
}

extern "C" void kernel_launch(void* const* d_in, const int* in_sizes, int n_in,
                              void* d_out, int out_size, void* d_ws, size_t ws_size,
                              hipStream_t stream) {
    const float* x  = (const float*)d_in[0];
    const float* pe = (const float*)d_in[1];
    const int*   dl = (const int*)d_in[2];
    float*       out = (float*)d_out;

    const int n_seg = in_sizes[2];           // 512 (<= 512 for LDS tables)
    const long n4 = (long)out_size / 4;      // 8,388,608 float4

    // 1024 blocks x 512 threads -> 16 grid-stride iterations (8 unrolled-x2);
    // ~4 blocks/CU resident, ~6 KB LDS, tiny VGPR footprint.
    pe_fused_kernel<<<1024, 512, 0, stream>>>(
        (const float4*)x, (const float4*)pe, dl, n_seg, (float4*)out, n4);
}

// Round 4
// 49.009 us; speedup vs baseline: 1.0365x; 1.0365x over previous
//
#include <hip/hip_runtime.h>

typedef float f4 __attribute__((ext_vector_type(4)));

// out[row][c] = x[row][c] + pe[row - seg_start(row)][c]
// O(1) segment lookup via bucket table + exclusive cumsum (LDS).
// Unroll x4 with batched loads for MLP; nontemporal stores to protect
// x's L3 residency. D_MODEL = 1024 floats = 256 f4 per row.
__global__ void __launch_bounds__(512)
pe_fused_kernel(const f4* __restrict__ x,
                const f4* __restrict__ pe,
                const int* __restrict__ dia_len, int n_seg,
                f4* __restrict__ out, long n4) {
    __shared__ int ex[513];      // exclusive cumsum; seg s = rows [ex[s], ex[s+1])
    __shared__ int seg_lo[512];  // segment containing row b*64 (also scan scratch)
    const int t = threadIdx.x;

    seg_lo[t] = (t < n_seg) ? dia_len[t] : 0;
    __syncthreads();
    #pragma unroll
    for (int off = 1; off < 512; off <<= 1) {
        int add = (t >= off) ? seg_lo[t - off] : 0;
        __syncthreads();
        seg_lo[t] += add;
        __syncthreads();
    }
    ex[t + 1] = seg_lo[t];
    if (t == 0) ex[0] = 0;
    __syncthreads();
    if (t < n_seg) {
        const int st = ex[t], en = ex[t + 1];
        for (int b = (st + 63) >> 6; (b << 6) < en; ++b) seg_lo[b] = t;
    }
    __syncthreads();

    const long stride = (long)gridDim.x * blockDim.x;
    long i = (long)blockIdx.x * blockDim.x + threadIdx.x;

    // position-within-segment for a row (2 dependent LDS reads, 0-iter while)
    #define PE_POS(ROW, P)                                            \
        int P;                                                        \
        {                                                             \
            int s_ = seg_lo[(ROW) >> 6];                              \
            while (ex[s_ + 1] <= (ROW)) ++s_;                         \
            P = (ROW) - ex[s_];                                       \
        }

    for (; i + 3 * stride < n4; i += 4 * stride) {
        const long i0 = i, i1 = i + stride, i2 = i + 2 * stride, i3 = i + 3 * stride;
        const int r0 = (int)(i0 >> 8), r1 = (int)(i1 >> 8),
                  r2 = (int)(i2 >> 8), r3 = (int)(i3 >> 8);
        PE_POS(r0, p0) PE_POS(r1, p1) PE_POS(r2, p2) PE_POS(r3, p3)
        // batch all 8 loads before any arithmetic/stores
        const f4 a0 = x[i0], a1 = x[i1], a2 = x[i2], a3 = x[i3];
        const f4 b0 = pe[((long)p0 << 8) | (i0 & 255)];
        const f4 b1 = pe[((long)p1 << 8) | (i1 & 255)];
        const f4 b2 = pe[((long)p2 << 8) | (i2 & 255)];
        const f4 b3 = pe[((long)p3 << 8) | (i3 & 255)];
        __builtin_nontemporal_store(a0 + b0, &out[i0]);
        __builtin_nontemporal_store(a1 + b1, &out[i1]);
        __builtin_nontemporal_store(a2 + b2, &out[i2]);
        __builtin_nontemporal_store(a3 + b3, &out[i3]);
    }
    for (; i < n4; i += stride) {
        const int row = (int)(i >> 8);
        PE_POS(row, p)
        const f4 a = x[i];
        const f4 b = pe[((long)p << 8) | (i & 255)];
        __builtin_nontemporal_store(a + b, &out[i]);
    }
    #undef PE_POS
}

extern "C" void kernel_launch(void* const* d_in, const int* in_sizes, int n_in,
                              void* d_out, int out_size, void* d_ws, size_t ws_size,
                              hipStream_t stream) {
    const float* x  = (const float*)d_in[0];
    const float* pe = (const float*)d_in[1];
    const int*   dl = (const int*)d_in[2];

    const int n_seg = in_sizes[2];           // 512 (<= 512 for LDS tables)
    const long n4 = (long)out_size / 4;      // 8,388,608 f4 -> 16 iters/thread

    pe_fused_kernel<<<1024, 512, 0, stream>>>(
        (const f4*)x, (const f4*)pe, dl, n_seg, (f4*)d_out, n4);
}

// Round 5
// 48.451 us; speedup vs baseline: 1.0484x; 1.0115x over previous
//
#include <hip/hip_runtime.h>

typedef float f4 __attribute__((ext_vector_type(4)));

// out[row][c] = x[row][c] + pe[row - seg_start(row)][c]
// O(1) segment lookup via bucket table + exclusive cumsum (LDS).
// Unroll x4; sched_barrier pins all 8 loads before any add/store so
// 8 x 16B loads stay in flight per thread (MLP), VGPR ~48 keeps full occ.
__global__ void __launch_bounds__(512)
pe_fused_kernel(const f4* __restrict__ x,
                const f4* __restrict__ pe,
                const int* __restrict__ dia_len, int n_seg,
                f4* __restrict__ out, long n4) {
    __shared__ int ex[513];      // exclusive cumsum; seg s = rows [ex[s], ex[s+1])
    __shared__ int seg_lo[512];  // segment containing row b*64 (also scan scratch)
    const int t = threadIdx.x;

    seg_lo[t] = (t < n_seg) ? dia_len[t] : 0;
    __syncthreads();
    #pragma unroll
    for (int off = 1; off < 512; off <<= 1) {
        int add = (t >= off) ? seg_lo[t - off] : 0;
        __syncthreads();
        seg_lo[t] += add;
        __syncthreads();
    }
    ex[t + 1] = seg_lo[t];
    if (t == 0) ex[0] = 0;
    __syncthreads();
    if (t < n_seg) {
        const int st = ex[t], en = ex[t + 1];
        for (int b = (st + 63) >> 6; (b << 6) < en; ++b) seg_lo[b] = t;
    }
    __syncthreads();

    const long stride = (long)gridDim.x * blockDim.x;
    long i = (long)blockIdx.x * blockDim.x + threadIdx.x;

    // position-within-segment for a row (2 dependent LDS reads, 0-iter while)
    #define PE_POS(ROW, P)                                            \
        int P;                                                        \
        {                                                             \
            int s_ = seg_lo[(ROW) >> 6];                              \
            while (ex[s_ + 1] <= (ROW)) ++s_;                         \
            P = (ROW) - ex[s_];                                       \
        }

    for (; i + 3 * stride < n4; i += 4 * stride) {
        const long i0 = i, i1 = i + stride, i2 = i + 2 * stride, i3 = i + 3 * stride;
        const int r0 = (int)(i0 >> 8), r1 = (int)(i1 >> 8),
                  r2 = (int)(i2 >> 8), r3 = (int)(i3 >> 8);
        PE_POS(r0, p0) PE_POS(r1, p1) PE_POS(r2, p2) PE_POS(r3, p3)
        // batch all 8 global loads ...
        const f4 a0 = x[i0], a1 = x[i1], a2 = x[i2], a3 = x[i3];
        const f4 b0 = pe[((long)p0 << 8) | (i0 & 255)];
        const f4 b1 = pe[((long)p1 << 8) | (i1 & 255)];
        const f4 b2 = pe[((long)p2 << 8) | (i2 & 255)];
        const f4 b3 = pe[((long)p3 << 8) | (i3 & 255)];
        // ... and forbid the scheduler from sinking them past this point
        __builtin_amdgcn_sched_barrier(0);
        __builtin_nontemporal_store(a0 + b0, &out[i0]);
        __builtin_nontemporal_store(a1 + b1, &out[i1]);
        __builtin_nontemporal_store(a2 + b2, &out[i2]);
        __builtin_nontemporal_store(a3 + b3, &out[i3]);
    }
    for (; i < n4; i += stride) {
        const int row = (int)(i >> 8);
        PE_POS(row, p)
        const f4 a = x[i];
        const f4 b = pe[((long)p << 8) | (i & 255)];
        __builtin_nontemporal_store(a + b, &out[i]);
    }
    #undef PE_POS
}

extern "C" void kernel_launch(void* const* d_in, const int* in_sizes, int n_in,
                              void* d_out, int out_size, void* d_ws, size_t ws_size,
                              hipStream_t stream) {
    const float* x  = (const float*)d_in[0];
    const float* pe = (const float*)d_in[1];
    const int*   dl = (const int*)d_in[2];

    const int n_seg = in_sizes[2];           // 512 (<= 512 for LDS tables)
    const long n4 = (long)out_size / 4;      // 8,388,608 f4 -> 16 per thread

    pe_fused_kernel<<<1024, 512, 0, stream>>>(
        (const f4*)x, (const f4*)pe, dl, n_seg, (f4*)d_out, n4);
}